// Round 5
// baseline (4097.995 us; speedup 1.0000x reference)
//
#include <hip/hip_runtime.h>

#define NB 64      // batch
#define NT 512     // time
#define ND 512     // input dim
#define NH 768     // hidden
#define KTOT 1280  // ND + NH
#define NG 3072    // 4*NH
#define NROW (NB * NT)  // 32768 rows of x
#define NHG 48          // h-groups (NH/16)
#define NCG 192         // col-groups (NG/16)
#define NKS 40          // k-slices (KTOT/32)

typedef short bf16x8 __attribute__((ext_vector_type(8)));
typedef float f32x4 __attribute__((ext_vector_type(4)));
typedef _Float16 f16x4 __attribute__((ext_vector_type(4)));

__device__ __forceinline__ unsigned short f2b(float f) {
    unsigned int u; __builtin_memcpy(&u, &f, 4);
    u = u + 0x7FFFu + ((u >> 16) & 1u);   // round-to-nearest-even
    return (unsigned short)(u >> 16);
}
__device__ __forceinline__ float sigmoidf_(float x) { return 1.f / (1.f + __expf(-x)); }
__device__ __forceinline__ float tanhf_(float x) { return 2.f / (1.f + __expf(-2.f * x)) - 1.f; }

// -------- W transpose+convert: W[KTOT][NG] f32 -> WTf fragment-ordered bf16 --------
// WTf[cg][ks][l][j] = W[ks*32 + (l>>4)*8 + j][cg*16 + (l&15)]
__global__ __launch_bounds__(256) void transpose_w(const float* __restrict__ W,
                                                   unsigned short* __restrict__ WTf) {
    __shared__ float tile[64][65];
    int bx = blockIdx.x % (NG / 64);   // col tile
    int by = blockIdx.x / (NG / 64);   // k tile
    int cb = bx * 64, kb = by * 64;
    int tid = threadIdx.x;
    {
        int r = tid >> 2;
        int coff = (tid & 3) * 16;
        const float* src = W + (size_t)(kb + r) * NG + cb + coff;
#pragma unroll
        for (int i = 0; i < 16; i += 4) {
            float4 v = *(const float4*)(src + i);
            tile[coff + i][r] = v.x; tile[coff + i + 1][r] = v.y;
            tile[coff + i + 2][r] = v.z; tile[coff + i + 3][r] = v.w;
        }
    }
    __syncthreads();
#pragma unroll
    for (int it = 0; it < 2; ++it) {
        int id = tid + it * 256;
        int ch = id >> 6;                 // 0..7
        int l = id & 63;
        int cgi = ch & 3, ksi = ch >> 2;
        int c = cgi * 16 + (l & 15);
        int k = ksi * 32 + ((l >> 4) * 8);
        bf16x8 o;
#pragma unroll
        for (int j = 0; j < 8; ++j) o[j] = (short)f2b(tile[c][k + j]);
        size_t cg = (size_t)(cb / 16) + cgi;
        size_t ks = (size_t)(kb / 32) + ksi;
        *(bf16x8*)(WTf + ((cg * NKS + ks) * 64 + l) * 8) = o;
    }
}

// -------- x f32 -> bf16 (mode 1 fallback) --------
__global__ __launch_bounds__(256) void convert_x(const float* __restrict__ src,
                                                 unsigned short* __restrict__ dst, int n8) {
    int i = blockIdx.x * 256 + threadIdx.x;
    if (i < n8) {
        const float4* s = (const float4*)(src + (size_t)i * 8);
        float4 v0 = s[0], v1 = s[1];
        bf16x8 o;
        o[0] = (short)f2b(v0.x); o[1] = (short)f2b(v0.y);
        o[2] = (short)f2b(v0.z); o[3] = (short)f2b(v0.w);
        o[4] = (short)f2b(v1.x); o[5] = (short)f2b(v1.y);
        o[6] = (short)f2b(v1.z); o[7] = (short)f2b(v1.w);
        *(bf16x8*)(dst + (size_t)i * 8) = o;
    }
}

// -------- precompute x-part gates (mode 2, f16 Gx, ~403MB) --------
// Gx layout = MFMA C-fragment natural order:
//   [dir][mblk(512)][nc(12)][gate(4)][nt(4)][m(4)][lane(64)][4] f16
__global__ __launch_bounds__(256) void gemm_xw(
    const float* __restrict__ seq,
    const unsigned short* __restrict__ WTf,
    const float* __restrict__ b_fw,
    const float* __restrict__ b_bw,
    _Float16* __restrict__ Gx) {
    __shared__ unsigned short Albs[64 * 522];    // odd dword pitch -> <=2-way
    int blk = blockIdx.x;
    int dir = blk >> 9;
    int mbi = blk & 511;
    int mb = mbi * 64;
    const float* bias = dir ? b_bw : b_fw;
    int tid = threadIdx.x;
    {
        int r = tid >> 2;
        int c = tid & 3;
        const float* src = seq + (size_t)(mb + r) * ND;
#pragma unroll
        for (int i = 0; i < 16; ++i) {
            int k = c * 8 + i * 32;
            float4 v0 = *(const float4*)(src + k);
            float4 v1 = *(const float4*)(src + k + 4);
            bf16x8 o;
            o[0] = (short)f2b(v0.x); o[1] = (short)f2b(v0.y);
            o[2] = (short)f2b(v0.z); o[3] = (short)f2b(v0.w);
            o[4] = (short)f2b(v1.x); o[5] = (short)f2b(v1.y);
            o[6] = (short)f2b(v1.z); o[7] = (short)f2b(v1.w);
            *(bf16x8*)&Albs[r * 522 + k] = o;
        }
    }
    __syncthreads();
    int lane = tid & 63, wave = tid >> 6;
    int r0 = lane & 15, qq = lane >> 4, q8 = qq * 8;
    _Float16* gbase = Gx + (size_t)(dir * 512 + mbi) * 196608;
#pragma unroll 1
    for (int nc = 0; nc < 12; ++nc) {
        int colbase = wave * NH + nc * 64;       // gate == wave
        f32x4 acc[4][4];
#pragma unroll
        for (int nt = 0; nt < 4; ++nt) {
            float bv = bias[colbase + nt * 16 + r0] + (wave == 2 ? 1.0f : 0.0f);
#pragma unroll
            for (int m = 0; m < 4; ++m) {
                acc[m][nt][0] = bv; acc[m][nt][1] = bv;
                acc[m][nt][2] = bv; acc[m][nt][3] = bv;
            }
        }
        const unsigned short* fpre = WTf +
            ((size_t)(dir * NCG + wave * NHG + nc * 4) * NKS) * 512 + (size_t)lane * 8;
#pragma unroll
        for (int ks = 0; ks < 16; ++ks) {
            bf16x8 a[4], bb[4];
#pragma unroll
            for (int m = 0; m < 4; ++m)
                a[m] = *(const bf16x8*)&Albs[(m * 16 + r0) * 522 + ks * 32 + q8];
#pragma unroll
            for (int nt = 0; nt < 4; ++nt)
                bb[nt] = *(const bf16x8*)(fpre + ((size_t)nt * NKS + ks) * 512);
#pragma unroll
            for (int m = 0; m < 4; ++m)
#pragma unroll
                for (int nt = 0; nt < 4; ++nt)
                    acc[m][nt] = __builtin_amdgcn_mfma_f32_16x16x32_bf16(a[m], bb[nt], acc[m][nt], 0, 0, 0);
        }
#pragma unroll
        for (int nt = 0; nt < 4; ++nt) {
#pragma unroll
            for (int m = 0; m < 4; ++m) {
                f16x4 o;
                o[0] = (_Float16)acc[m][nt][0]; o[1] = (_Float16)acc[m][nt][1];
                o[2] = (_Float16)acc[m][nt][2]; o[3] = (_Float16)acc[m][nt][3];
                *(f16x4*)(gbase + (size_t)((((nc * 4 + wave) * 4 + nt) * 4 + m) * 64 + lane) * 4) = o;
            }
        }
    }
}

// ---------------- persistent bidirectional LSTM ----------------
// 192 blocks = dir(2) x bgroup(2) x hgroup(48); 256 threads; 1 block/CU.
// Latency-chain edition (round 5):
//  * out/h_final stores moved AFTER the barrier arrive (off the S3 drain path;
//    only the 2x2B sc1 h-stores are drained before arrive).
//  * per-wave poll replaces tid0-poll + trailing block barrier (S3 already
//    guarantees all gl/Af reads of this step are done before anyone arrives,
//    so a wave may start next-step staging as soon as it observes the count).
//  * Wh B-fragments hoisted into registers wb[24] (96 VGPR) from LDS once;
//    inner loop is 2 ds_read_b128 + 2 MFMA per ks.
__global__ __launch_bounds__(256, 1) void lstm_persistent(
    const float* __restrict__ seq,
    const unsigned short* __restrict__ xbf,
    int mode,                                    // 0: x f32, 1: x bf16, 2: Gx f16
    const int* __restrict__ seq_len,
    const unsigned short* __restrict__ WTf,      // fragment-ordered
    const float* __restrict__ bias_fw,
    const float* __restrict__ bias_bw,
    const _Float16* __restrict__ Gx,             // mode 2
    unsigned short* __restrict__ hbufs,          // [3][2][NB][NH] bf16
    float* __restrict__ h_final,                 // [2][NB][NH] f32
    float* __restrict__ out,                     // [NB][NT][2*NH] f32
    unsigned int* __restrict__ barrier_cnts)     // 4 counters, 256B apart
{
    extern __shared__ char smem[];
    unsigned short* Whf = (unsigned short*)smem;               // 98,304B
    unsigned short* Af  = (unsigned short*)(smem + 98304);     // 49,152B
    float* gl = (float*)(smem + 147456);                       // 8,704B

    int bid = blockIdx.x;
    int hgroup = bid % NHG;
    int bgroup = (bid / NHG) & 1;
    int dir = bid / (2 * NHG);
    int grp = bid / NHG;                         // barrier group 0..3
    int b0 = bgroup * 32;
    int hbase = hgroup * 16;
    int tid = threadIdx.x;
    int lane = tid & 63;
    int wave = tid >> 6;                         // = gate
    int r0 = lane & 15;
    int qq = lane >> 4;
    int q8 = qq * 8;

    const float* bias = dir ? bias_bw : bias_fw;
    int col = wave * NH + hbase + r0;
    float bv = bias[col] + (wave == 2 ? 1.0f : 0.0f);

    // ---- fill Whf (fragment order) from WTf ----
    {
#pragma unroll
        for (int i = 0; i < 24; ++i) {
            int g = i / 6;
            int ks = wave + (i % 6) * 4;
            const unsigned short* src = WTf +
                ((size_t)(dir * NCG + g * NHG + hgroup) * NKS + 16 + ks) * 512 + (size_t)lane * 8;
            *(bf16x8*)(Whf + ((size_t)tid + (size_t)i * 256) * 8) = *(const bf16x8*)src;
        }
    }

    // ---- epilogue constants ----
    int ebl0 = tid >> 4;
    int ehl = tid & 15;
    int hidx = hbase + ehl;
    int Lb[2]; Lb[0] = seq_len[b0 + ebl0]; Lb[1] = seq_len[b0 + ebl0 + 16];
    float c_reg[2] = {0.f, 0.f};
    unsigned short h_reg[2] = {0, 0};
    float nhv[2] = {0.f, 0.f};

    // ---- per-step x state ----
    f32x4 ax0, ax1;                              // modes 0/1: bias + x-part
    float gxv[8];                                // mode 2
    int Rlo[8], Roff[8];
    const _Float16* GxK;
    int Lx[2];                                   // modes 0/1 staging

    if (mode == 2) {
        size_t K0 = (size_t)dir * 100663296 + (size_t)(hgroup >> 2) * 16384 +
                    (size_t)wave * 4096 + (size_t)(hgroup & 3) * 1024 + (size_t)r0 * 4;
        GxK = Gx + K0;
#pragma unroll
        for (int i = 0; i < 8; ++i) {
            int br = b0 + (i >> 2) * 16 + qq * 4 + (i & 3);
            int L = seq_len[br];
            Rlo[i] = br * NT;
            Roff[i] = dir ? (L - 1) : 0;
        }
    } else {
        Lx[0] = seq_len[b0 + r0];
        Lx[1] = seq_len[b0 + 16 + r0];
    }

    auto gxload = [&](int stepn) {
#pragma unroll
        for (int i = 0; i < 8; ++i) {
            int tn = dir ? (Roff[i] - stepn) : stepn;
            tn = tn < 0 ? 0 : (tn > NT - 1 ? NT - 1 : tn);
            int R = Rlo[i] + tn;
            size_t a = (size_t)(R >> 6) * 196608 +
                       (size_t)(((R >> 4) & 3) * 256 + ((R >> 2) & 3) * 64 + (R & 3));
            gxv[i] = (float)GxK[a];
        }
    };

    const unsigned short* fbx = WTf +
        ((size_t)(dir * NCG + wave * NHG + hgroup) * NKS) * 512 + (size_t)lane * 8;

    auto xwindow = [&](int stepn) {
#pragma unroll
        for (int i = 0; i < 8; ++i) {
            int m = i >> 2;
            int ks = wave + (i & 3) * 4;
            int row = b0 + m * 16 + r0;
            int tn = dir ? (Lx[m] - 1 - stepn) : stepn;
            tn = tn < 0 ? 0 : (tn > NT - 1 ? NT - 1 : tn);
            unsigned short* dst = Af + ((size_t)(m * 24 + ks) * 64 + lane) * 8;
            if (mode == 1) {
                *(bf16x8*)dst = *(const bf16x8*)(xbf + ((size_t)row * NT + tn) * ND + ks * 32 + q8);
            } else {
                const float* xr = seq + ((size_t)row * NT + tn) * ND + ks * 32 + q8;
                float4 v0 = *(const float4*)xr, v1 = *(const float4*)(xr + 4);
                bf16x8 o;
                o[0] = (short)f2b(v0.x); o[1] = (short)f2b(v0.y);
                o[2] = (short)f2b(v0.z); o[3] = (short)f2b(v0.w);
                o[4] = (short)f2b(v1.x); o[5] = (short)f2b(v1.y);
                o[6] = (short)f2b(v1.z); o[7] = (short)f2b(v1.w);
                *(bf16x8*)dst = o;
            }
        }
        __syncthreads();
        ax0[0] = bv; ax0[1] = bv; ax0[2] = bv; ax0[3] = bv;
        ax1 = ax0;
        const unsigned short* afp = Af + (size_t)lane * 8;
#pragma unroll
        for (int ks = 0; ks < 16; ++ks) {
            bf16x8 a0 = *(const bf16x8*)(afp + ks * 512);
            bf16x8 a1 = *(const bf16x8*)(afp + 12288 + ks * 512);
            bf16x8 bx = *(const bf16x8*)(fbx + (size_t)ks * 512);
            ax0 = __builtin_amdgcn_mfma_f32_16x16x32_bf16(a0, bx, ax0, 0, 0, 0);
            ax1 = __builtin_amdgcn_mfma_f32_16x16x32_bf16(a1, bx, ax1, 0, 0, 0);
        }
    };

    if (mode == 2) gxload(0); else xwindow(0);
    __syncthreads();                             // Whf ready

    // ---- Wh B-fragments -> registers (from LDS, once) ----
    bf16x8 wb[24];
    {
        const unsigned short* wfp = Whf + (size_t)wave * 12288 + (size_t)lane * 8;
#pragma unroll
        for (int ks = 0; ks < 24; ++ks) wb[ks] = *(const bf16x8*)(wfp + ks * 512);
    }

    unsigned int* cnt = barrier_cnts + grp * 64; // 256B apart

    for (int step = 0; step < NT; ++step) {
        const unsigned short* hin = hbufs + (size_t)(step % 3) * (2 * NB * NH) + (size_t)dir * NB * NH;
        unsigned short* hout      = hbufs + (size_t)((step + 1) % 3) * (2 * NB * NH) + (size_t)dir * NB * NH;

        // ---- stage h into Af (fragment order): sc1 loads -> b128 LDS writes ----
        {
            const unsigned long long* hb =
                (const unsigned long long*)(hin + (size_t)(b0 + r0) * NH + q8);
            unsigned long long hA[24];
#pragma unroll
            for (int i = 0; i < 12; ++i) {
                int off8 = ((i / 6) * 16 * NH + (wave + (i % 6) * 4) * 32) >> 2;
                hA[2 * i]     = __hip_atomic_load(hb + off8,     __ATOMIC_RELAXED, __HIP_MEMORY_SCOPE_AGENT);
                hA[2 * i + 1] = __hip_atomic_load(hb + off8 + 1, __ATOMIC_RELAXED, __HIP_MEMORY_SCOPE_AGENT);
            }
#pragma unroll
            for (int i = 0; i < 12; ++i) {
                union { unsigned long long u[2]; bf16x8 v; } t;
                t.u[0] = hA[2 * i]; t.u[1] = hA[2 * i + 1];
                *(bf16x8*)(Af + ((size_t)tid + (size_t)i * 256) * 8) = t.v;
            }
        }
        __syncthreads();                          // S1

        // ---- h-GEMM: acc = (bias + x-part) + h @ Wh (B in regs) ----
        f32x4 acc0, acc1;
        if (mode == 2) {
            acc0[0] = gxv[0]; acc0[1] = gxv[1]; acc0[2] = gxv[2]; acc0[3] = gxv[3];
            acc1[0] = gxv[4]; acc1[1] = gxv[5]; acc1[2] = gxv[6]; acc1[3] = gxv[7];
        } else {
            acc0 = ax0; acc1 = ax1;
        }
        {
            const unsigned short* afp = Af + (size_t)lane * 8;
#pragma unroll
            for (int ks = 0; ks < 24; ++ks) {
                bf16x8 a0 = *(const bf16x8*)(afp + ks * 512);
                bf16x8 a1 = *(const bf16x8*)(afp + 12288 + ks * 512);
                acc0 = __builtin_amdgcn_mfma_f32_16x16x32_bf16(a0, wb[ks], acc0, 0, 0, 0);
                acc1 = __builtin_amdgcn_mfma_f32_16x16x32_bf16(a1, wb[ks], acc1, 0, 0, 0);
            }
        }

        // C/D: col = lane&15, row = (lane>>4)*4 + reg; gl pitch 17
#pragma unroll
        for (int r = 0; r < 4; ++r) {
            gl[(wave * 32 + qq * 4 + r) * 17 + r0] = acc0[r];
            gl[(wave * 32 + 16 + qq * 4 + r) * 17 + r0] = acc1[r];
        }
        __syncthreads();                          // S2

        // ---- epilogue: cell update; ONLY the sc1 h-stores stay pre-arrive ----
#pragma unroll
        for (int it = 0; it < 2; ++it) {
            int bl = ebl0 + it * 16;
            int bb = b0 + bl;
            if (step < Lb[it]) {
                float gi = gl[(0 * 32 + bl) * 17 + ehl];
                float gj = gl[(1 * 32 + bl) * 17 + ehl];
                float gf = gl[(2 * 32 + bl) * 17 + ehl];
                float go = gl[(3 * 32 + bl) * 17 + ehl];
                float nc = c_reg[it] * sigmoidf_(gf) + sigmoidf_(gi) * tanhf_(gj);
                float nh = tanhf_(nc) * sigmoidf_(go);
                c_reg[it] = nc;
                h_reg[it] = f2b(nh);
                nhv[it] = nh;
            }
            __hip_atomic_store(&hout[(size_t)bb * NH + hidx], h_reg[it],
                               __ATOMIC_RELAXED, __HIP_MEMORY_SCOPE_AGENT);
        }

        __syncthreads();                          // S3: drain h-stores; all gl/Af reads done

        if (tid == 0)
            __hip_atomic_fetch_add(cnt, 1u, __ATOMIC_RELEASE, __HIP_MEMORY_SCOPE_WORKGROUP);

        // ---- post-arrive (hidden under barrier wait) ----
        if (mode == 2) gxload(step + 1); else xwindow(step + 1);

        // out / h_final stores: fire-and-forget until kernel end
#pragma unroll
        for (int it = 0; it < 2; ++it) {
            int bb = b0 + ebl0 + it * 16;
            if (step < Lb[it]) {
                int t_out = dir ? (Lb[it] - 1 - step) : step;
                out[((size_t)bb * NT + t_out) * (2 * NH) + dir * NH + hidx] = nhv[it];
                if (step == Lb[it] - 1)
                    h_final[((size_t)dir * NB + bb) * NH + hidx] = nhv[it];
            } else {
                out[((size_t)bb * NT + step) * (2 * NH) + dir * NH + hidx] = 0.f;
            }
        }

        // ---- per-wave poll: wave proceeds as soon as it observes the count ----
        {
            unsigned int tgt = 48u * (unsigned)(step + 1);
            if (lane == 0) {
                while (__hip_atomic_load(cnt, __ATOMIC_RELAXED, __HIP_MEMORY_SCOPE_AGENT) < tgt)
                    __builtin_amdgcn_s_sleep(2);
            }
        }
        if (mode != 2) __syncthreads();           // Af x-staging race guard (modes 0/1 only)
    }
}

// ---------------- final hidden state (f32) -> d_out tail ----------------
__global__ __launch_bounds__(256) void write_state(const float* __restrict__ h_final,
                                                   float* __restrict__ out_state) {
    int i = blockIdx.x * 256 + threadIdx.x;      // over 2*NB*NH
    if (i < 2 * NB * NH) {
        int dir = i / (NB * NH);
        int rem = i - dir * (NB * NH);
        int b = rem / NH, h = rem - (rem / NH) * NH;
        out_state[(size_t)b * (2 * NH) + dir * NH + h] = h_final[i];
    }
}

extern "C" void kernel_launch(void* const* d_in, const int* in_sizes, int n_in,
                              void* d_out, int out_size, void* d_ws, size_t ws_size,
                              hipStream_t stream) {
    const float* seq   = (const float*)d_in[0];
    const int* seq_len = (const int*)d_in[1];
    const float* W_fw  = (const float*)d_in[2];
    const float* b_fw  = (const float*)d_in[3];
    const float* W_bw  = (const float*)d_in[4];
    const float* b_bw  = (const float*)d_in[5];
    float* out = (float*)d_out;

    char* ws = (char*)d_ws;
    size_t off = 0;
    unsigned short* WTf = (unsigned short*)(ws + off); off += (size_t)2 * NG * KTOT * 2; // 15,728,640
    unsigned short* hbufs = (unsigned short*)(ws + off);
    size_t hbuf_bytes = (size_t)3 * 2 * NB * NH * 2;   off += hbuf_bytes;                // 589,824
    float* h_final = (float*)(ws + off);
    size_t hf_bytes = (size_t)2 * NB * NH * 4;         off += hf_bytes;                  // 393,216
    unsigned int* barrier_cnts = (unsigned int*)(ws + off);
    size_t bar_bytes = 1024;                           off += bar_bytes;

    _Float16* Gx = (_Float16*)(ws + off);
    size_t gx_bytes = (size_t)2 * 512 * 196608 * 2;      // 402,653,184
    unsigned short* xbf = (unsigned short*)(ws + off);
    size_t xbf_bytes = (size_t)NB * NT * ND * 2;         // 33,554,432

    int mode = (ws_size >= off + gx_bytes) ? 2
             : ((ws_size >= off + xbf_bytes) ? 1 : 0);

    hipMemsetAsync(hbufs, 0, hbuf_bytes + hf_bytes + bar_bytes, stream);

    transpose_w<<<(KTOT / 64) * (NG / 64), 256, 0, stream>>>(W_fw, WTf);
    transpose_w<<<(KTOT / 64) * (NG / 64), 256, 0, stream>>>(W_bw, WTf + (size_t)NG * KTOT);

    if (mode == 2) {
        gemm_xw<<<1024, 256, 0, stream>>>(seq, WTf, b_fw, b_bw, Gx);
    } else if (mode == 1) {
        int n8 = NB * NT * ND / 8;
        convert_x<<<(n8 + 255) / 256, 256, 0, stream>>>(seq, xbf, n8);
    }

    size_t smem_bytes = 156160;                  // Whf 98,304 + Af 49,152 + gl 8,704
    lstm_persistent<<<192, 256, smem_bytes, stream>>>(
        seq, xbf, mode, seq_len, WTf, b_fw, b_bw, Gx,
        hbufs, h_final, out, barrier_cnts);

    write_state<<<(2 * NB * NH + 255) / 256, 256, 0, stream>>>(
        h_final, out + (size_t)NB * NT * 2 * NH);
}

// Round 6
// 4062.832 us; speedup vs baseline: 1.0087x; 1.0087x over previous
//
#include <hip/hip_runtime.h>

#define NB 64      // batch
#define NT 512     // time
#define ND 512     // input dim
#define NH 768     // hidden
#define KTOT 1280  // ND + NH
#define NG 3072    // 4*NH
#define NROW (NB * NT)  // 32768 rows of x
#define NHG 48          // h-groups (NH/16)
#define NCG 192         // col-groups (NG/16)
#define NKS 40          // k-slices (KTOT/32)

typedef short bf16x8 __attribute__((ext_vector_type(8)));
typedef float f32x4 __attribute__((ext_vector_type(4)));
typedef _Float16 f16x4 __attribute__((ext_vector_type(4)));

__device__ __forceinline__ unsigned short f2b(float f) {
    unsigned int u; __builtin_memcpy(&u, &f, 4);
    u = u + 0x7FFFu + ((u >> 16) & 1u);   // round-to-nearest-even
    return (unsigned short)(u >> 16);
}
__device__ __forceinline__ float sigmoidf_(float x) { return 1.f / (1.f + __expf(-x)); }
__device__ __forceinline__ float tanhf_(float x) { return 2.f / (1.f + __expf(-2.f * x)) - 1.f; }

// -------- W transpose+convert: W[KTOT][NG] f32 -> WTf fragment-ordered bf16 --------
// WTf[cg][ks][l][j] = W[ks*32 + (l>>4)*8 + j][cg*16 + (l&15)]
__global__ __launch_bounds__(256) void transpose_w(const float* __restrict__ W,
                                                   unsigned short* __restrict__ WTf) {
    __shared__ float tile[64][65];
    int bx = blockIdx.x % (NG / 64);   // col tile
    int by = blockIdx.x / (NG / 64);   // k tile
    int cb = bx * 64, kb = by * 64;
    int tid = threadIdx.x;
    {
        int r = tid >> 2;
        int coff = (tid & 3) * 16;
        const float* src = W + (size_t)(kb + r) * NG + cb + coff;
#pragma unroll
        for (int i = 0; i < 16; i += 4) {
            float4 v = *(const float4*)(src + i);
            tile[coff + i][r] = v.x; tile[coff + i + 1][r] = v.y;
            tile[coff + i + 2][r] = v.z; tile[coff + i + 3][r] = v.w;
        }
    }
    __syncthreads();
#pragma unroll
    for (int it = 0; it < 2; ++it) {
        int id = tid + it * 256;
        int ch = id >> 6;                 // 0..7
        int l = id & 63;
        int cgi = ch & 3, ksi = ch >> 2;
        int c = cgi * 16 + (l & 15);
        int k = ksi * 32 + ((l >> 4) * 8);
        bf16x8 o;
#pragma unroll
        for (int j = 0; j < 8; ++j) o[j] = (short)f2b(tile[c][k + j]);
        size_t cg = (size_t)(cb / 16) + cgi;
        size_t ks = (size_t)(kb / 32) + ksi;
        *(bf16x8*)(WTf + ((cg * NKS + ks) * 64 + l) * 8) = o;
    }
}

// -------- x f32 -> bf16 (mode 1 fallback) --------
__global__ __launch_bounds__(256) void convert_x(const float* __restrict__ src,
                                                 unsigned short* __restrict__ dst, int n8) {
    int i = blockIdx.x * 256 + threadIdx.x;
    if (i < n8) {
        const float4* s = (const float4*)(src + (size_t)i * 8);
        float4 v0 = s[0], v1 = s[1];
        bf16x8 o;
        o[0] = (short)f2b(v0.x); o[1] = (short)f2b(v0.y);
        o[2] = (short)f2b(v0.z); o[3] = (short)f2b(v0.w);
        o[4] = (short)f2b(v1.x); o[5] = (short)f2b(v1.y);
        o[6] = (short)f2b(v1.z); o[7] = (short)f2b(v1.w);
        *(bf16x8*)(dst + (size_t)i * 8) = o;
    }
}

// -------- precompute x-part gates (mode 2, f16 Gx, ~403MB) --------
// Gx layout = MFMA C-fragment natural order:
//   [dir][mblk(512)][nc(12)][gate(4)][nt(4)][m(4)][lane(64)][4] f16
__global__ __launch_bounds__(256) void gemm_xw(
    const float* __restrict__ seq,
    const unsigned short* __restrict__ WTf,
    const float* __restrict__ b_fw,
    const float* __restrict__ b_bw,
    _Float16* __restrict__ Gx) {
    __shared__ unsigned short Albs[64 * 522];    // odd dword pitch -> <=2-way
    int blk = blockIdx.x;
    int dir = blk >> 9;
    int mbi = blk & 511;
    int mb = mbi * 64;
    const float* bias = dir ? b_bw : b_fw;
    int tid = threadIdx.x;
    {
        int r = tid >> 2;
        int c = tid & 3;
        const float* src = seq + (size_t)(mb + r) * ND;
#pragma unroll
        for (int i = 0; i < 16; ++i) {
            int k = c * 8 + i * 32;
            float4 v0 = *(const float4*)(src + k);
            float4 v1 = *(const float4*)(src + k + 4);
            bf16x8 o;
            o[0] = (short)f2b(v0.x); o[1] = (short)f2b(v0.y);
            o[2] = (short)f2b(v0.z); o[3] = (short)f2b(v0.w);
            o[4] = (short)f2b(v1.x); o[5] = (short)f2b(v1.y);
            o[6] = (short)f2b(v1.z); o[7] = (short)f2b(v1.w);
            *(bf16x8*)&Albs[r * 522 + k] = o;
        }
    }
    __syncthreads();
    int lane = tid & 63, wave = tid >> 6;
    int r0 = lane & 15, qq = lane >> 4, q8 = qq * 8;
    _Float16* gbase = Gx + (size_t)(dir * 512 + mbi) * 196608;
#pragma unroll 1
    for (int nc = 0; nc < 12; ++nc) {
        int colbase = wave * NH + nc * 64;       // gate == wave
        f32x4 acc[4][4];
#pragma unroll
        for (int nt = 0; nt < 4; ++nt) {
            float bv = bias[colbase + nt * 16 + r0] + (wave == 2 ? 1.0f : 0.0f);
#pragma unroll
            for (int m = 0; m < 4; ++m) {
                acc[m][nt][0] = bv; acc[m][nt][1] = bv;
                acc[m][nt][2] = bv; acc[m][nt][3] = bv;
            }
        }
        const unsigned short* fpre = WTf +
            ((size_t)(dir * NCG + wave * NHG + nc * 4) * NKS) * 512 + (size_t)lane * 8;
#pragma unroll
        for (int ks = 0; ks < 16; ++ks) {
            bf16x8 a[4], bb[4];
#pragma unroll
            for (int m = 0; m < 4; ++m)
                a[m] = *(const bf16x8*)&Albs[(m * 16 + r0) * 522 + ks * 32 + q8];
#pragma unroll
            for (int nt = 0; nt < 4; ++nt)
                bb[nt] = *(const bf16x8*)(fpre + ((size_t)nt * NKS + ks) * 512);
#pragma unroll
            for (int m = 0; m < 4; ++m)
#pragma unroll
                for (int nt = 0; nt < 4; ++nt)
                    acc[m][nt] = __builtin_amdgcn_mfma_f32_16x16x32_bf16(a[m], bb[nt], acc[m][nt], 0, 0, 0);
        }
#pragma unroll
        for (int nt = 0; nt < 4; ++nt) {
#pragma unroll
            for (int m = 0; m < 4; ++m) {
                f16x4 o;
                o[0] = (_Float16)acc[m][nt][0]; o[1] = (_Float16)acc[m][nt][1];
                o[2] = (_Float16)acc[m][nt][2]; o[3] = (_Float16)acc[m][nt][3];
                *(f16x4*)(gbase + (size_t)((((nc * 4 + wave) * 4 + nt) * 4 + m) * 64 + lane) * 4) = o;
            }
        }
    }
}

// ---------------- persistent bidirectional LSTM ----------------
// 192 blocks = dir(2) x bgroup(2) x hgroup(48); 256 threads; 1 block/CU.
// Round 6: round-4 sync skeleton (tid0 arrive -> prefetch -> tid0 poll -> S4;
// out/h_final pre-S3) + register-resident h-GEMM:
//  * hbufs stored in MFMA FRAGMENT order: [buf][dir][rb(4)][ks(24)][lane(64)][8].
//    Producer epilogue scatters its 2x2B sc1 stores into fragment positions;
//    consumer loads A-fragments straight into registers -> Af LDS staging and
//    the S1 barrier are gone (3 block barriers -> 2 per step).
//  * Wh B-fragments in registers wb[24] (LDS-sourced; r5 verified resident).
//  * h-loads software-pipelined in 4 chunks of 6 ks, 2 chunks in flight.
__global__ __launch_bounds__(256, 1) void lstm_persistent(
    const float* __restrict__ seq,
    const unsigned short* __restrict__ xbf,
    int mode,                                    // 0: x f32, 1: x bf16, 2: Gx f16
    const int* __restrict__ seq_len,
    const unsigned short* __restrict__ WTf,      // fragment-ordered
    const float* __restrict__ bias_fw,
    const float* __restrict__ bias_bw,
    const _Float16* __restrict__ Gx,             // mode 2
    unsigned short* __restrict__ hbufs,          // [3][2][4][24][64][8] bf16 (frag order)
    float* __restrict__ h_final,                 // [2][NB][NH] f32
    float* __restrict__ out,                     // [NB][NT][2*NH] f32
    unsigned int* __restrict__ barrier_cnts)     // 4 counters, 256B apart
{
    extern __shared__ char smem[];
    unsigned short* Whf = (unsigned short*)smem;               // 98,304B (prologue only)
    float* gl = (float*)(smem + 98304);                        // 8,704B

    int bid = blockIdx.x;
    int hgroup = bid % NHG;
    int bgroup = (bid / NHG) & 1;
    int dir = bid / (2 * NHG);
    int grp = bid / NHG;                         // barrier group 0..3
    int b0 = bgroup * 32;
    int hbase = hgroup * 16;
    int tid = threadIdx.x;
    int lane = tid & 63;
    int wave = tid >> 6;                         // = gate
    int r0 = lane & 15;
    int qq = lane >> 4;
    int q8 = qq * 8;

    const float* bias = dir ? bias_bw : bias_fw;
    int col = wave * NH + hbase + r0;
    float bv = bias[col] + (wave == 2 ? 1.0f : 0.0f);

    // ---- fill Whf (fragment order) from WTf, then hoist to registers ----
    {
#pragma unroll
        for (int i = 0; i < 24; ++i) {
            int g = i / 6;
            int ks = wave + (i % 6) * 4;
            const unsigned short* src = WTf +
                ((size_t)(dir * NCG + g * NHG + hgroup) * NKS + 16 + ks) * 512 + (size_t)lane * 8;
            *(bf16x8*)(Whf + ((size_t)tid + (size_t)i * 256) * 8) = *(const bf16x8*)src;
        }
    }

    // ---- epilogue constants ----
    int ebl0 = tid >> 4;
    int ehl = tid & 15;
    int hidx = hbase + ehl;
    int Lb[2]; Lb[0] = seq_len[b0 + ebl0]; Lb[1] = seq_len[b0 + ebl0 + 16];
    float c_reg[2] = {0.f, 0.f};
    unsigned short h_reg[2] = {0, 0};
    // fragment-order store offsets for this thread's two (bb, hidx) values
    size_t eoff[2];
#pragma unroll
    for (int it = 0; it < 2; ++it) {
        int bb = b0 + ebl0 + it * 16;
        eoff[it] = ((size_t)((bb >> 4) * 24 + (hidx >> 5)) * 64 +
                    (size_t)(((hidx >> 3) & 3) * 16 + (bb & 15))) * 8 + (hidx & 7);
    }

    // ---- per-step x state ----
    f32x4 ax0, ax1;                              // modes 0/1: bias + x-part
    float gxv[8];                                // mode 2
    int Rlo[8], Roff[8];
    const _Float16* GxK;
    int Lx[2];

    if (mode == 2) {
        size_t K0 = (size_t)dir * 100663296 + (size_t)(hgroup >> 2) * 16384 +
                    (size_t)wave * 4096 + (size_t)(hgroup & 3) * 1024 + (size_t)r0 * 4;
        GxK = Gx + K0;
#pragma unroll
        for (int i = 0; i < 8; ++i) {
            int br = b0 + (i >> 2) * 16 + qq * 4 + (i & 3);
            int L = seq_len[br];
            Rlo[i] = br * NT;
            Roff[i] = dir ? (L - 1) : 0;
        }
    } else {
        Lx[0] = seq_len[b0 + r0];
        Lx[1] = seq_len[b0 + 16 + r0];
    }

    auto gxload = [&](int stepn) {
#pragma unroll
        for (int i = 0; i < 8; ++i) {
            int tn = dir ? (Roff[i] - stepn) : stepn;
            tn = tn < 0 ? 0 : (tn > NT - 1 ? NT - 1 : tn);
            int R = Rlo[i] + tn;
            size_t a = (size_t)(R >> 6) * 196608 +
                       (size_t)(((R >> 4) & 3) * 256 + ((R >> 2) & 3) * 64 + (R & 3));
            gxv[i] = (float)GxK[a];
        }
    };

    const unsigned short* fbx = WTf +
        ((size_t)(dir * NCG + wave * NHG + hgroup) * NKS) * 512 + (size_t)lane * 8;

    // modes 0/1 fallback: register x-window (B-frags from global)
    auto xwindow = [&](int stepn) {
        ax0[0] = bv; ax0[1] = bv; ax0[2] = bv; ax0[3] = bv;
        ax1 = ax0;
#pragma unroll
        for (int m = 0; m < 2; ++m) {
            int row = b0 + m * 16 + r0;
            int tn = dir ? (Lx[m] - 1 - stepn) : stepn;
            tn = tn < 0 ? 0 : (tn > NT - 1 ? NT - 1 : tn);
#pragma unroll
            for (int ks = 0; ks < 16; ++ks) {
                bf16x8 av;
                if (mode == 1) {
                    av = *(const bf16x8*)(xbf + ((size_t)row * NT + tn) * ND + ks * 32 + q8);
                } else {
                    const float* xr = seq + ((size_t)row * NT + tn) * ND + ks * 32 + q8;
                    float4 v0 = *(const float4*)xr, v1 = *(const float4*)(xr + 4);
                    av[0] = (short)f2b(v0.x); av[1] = (short)f2b(v0.y);
                    av[2] = (short)f2b(v0.z); av[3] = (short)f2b(v0.w);
                    av[4] = (short)f2b(v1.x); av[5] = (short)f2b(v1.y);
                    av[6] = (short)f2b(v1.z); av[7] = (short)f2b(v1.w);
                }
                bf16x8 bx = *(const bf16x8*)(fbx + (size_t)ks * 512);
                if (m == 0) ax0 = __builtin_amdgcn_mfma_f32_16x16x32_bf16(av, bx, ax0, 0, 0, 0);
                else        ax1 = __builtin_amdgcn_mfma_f32_16x16x32_bf16(av, bx, ax1, 0, 0, 0);
            }
        }
    };

    if (mode == 2) gxload(0); else xwindow(0);
    __syncthreads();                             // Whf ready

    // ---- Wh B-fragments -> registers (from LDS, once) ----
    bf16x8 wb[24];
    {
        const unsigned short* wfp = Whf + (size_t)wave * 12288 + (size_t)lane * 8;
#pragma unroll
        for (int ks = 0; ks < 24; ++ks) wb[ks] = *(const bf16x8*)(wfp + ks * 512);
    }

    unsigned int* cnt = barrier_cnts + grp * 64; // 256B apart
    int rb0 = bgroup * 2;

    for (int step = 0; step < NT; ++step) {
        const unsigned long long* hin64 = (const unsigned long long*)
            (hbufs + (size_t)(step % 3) * (2 * NB * NH) + (size_t)dir * NB * NH);
        unsigned short* hout = hbufs + (size_t)((step + 1) % 3) * (2 * NB * NH) + (size_t)dir * NB * NH;

        // ---- h A-fragments: direct sc1 loads, 4 chunks of 6 ks, 2 in flight ----
        unsigned long long huA[24], huB[24];
        auto issue = [&](int c, unsigned long long* hu) {
#pragma unroll
            for (int i = 0; i < 6; ++i) {
                int ks = c * 6 + i;
                size_t o0 = ((size_t)(rb0 * 24 + ks) * 64 + lane) * 2;
                size_t o1 = ((size_t)((rb0 + 1) * 24 + ks) * 64 + lane) * 2;
                hu[4 * i]     = __hip_atomic_load(hin64 + o0,     __ATOMIC_RELAXED, __HIP_MEMORY_SCOPE_AGENT);
                hu[4 * i + 1] = __hip_atomic_load(hin64 + o0 + 1, __ATOMIC_RELAXED, __HIP_MEMORY_SCOPE_AGENT);
                hu[4 * i + 2] = __hip_atomic_load(hin64 + o1,     __ATOMIC_RELAXED, __HIP_MEMORY_SCOPE_AGENT);
                hu[4 * i + 3] = __hip_atomic_load(hin64 + o1 + 1, __ATOMIC_RELAXED, __HIP_MEMORY_SCOPE_AGENT);
            }
        };

        f32x4 acc0, acc1;
        if (mode == 2) {
            acc0[0] = gxv[0]; acc0[1] = gxv[1]; acc0[2] = gxv[2]; acc0[3] = gxv[3];
            acc1[0] = gxv[4]; acc1[1] = gxv[5]; acc1[2] = gxv[6]; acc1[3] = gxv[7];
        } else {
            acc0 = ax0; acc1 = ax1;
        }

        auto consume = [&](int c, const unsigned long long* hu) {
#pragma unroll
            for (int i = 0; i < 6; ++i) {
                int ks = c * 6 + i;
                union { unsigned long long u[2]; bf16x8 v; } fa0, fa1;
                fa0.u[0] = hu[4 * i];     fa0.u[1] = hu[4 * i + 1];
                fa1.u[0] = hu[4 * i + 2]; fa1.u[1] = hu[4 * i + 3];
                acc0 = __builtin_amdgcn_mfma_f32_16x16x32_bf16(fa0.v, wb[ks], acc0, 0, 0, 0);
                acc1 = __builtin_amdgcn_mfma_f32_16x16x32_bf16(fa1.v, wb[ks], acc1, 0, 0, 0);
            }
        };

        issue(0, huA);
        issue(1, huB);
        consume(0, huA); issue(2, huA);
        consume(1, huB); issue(3, huB);
        consume(2, huA);
        consume(3, huB);

        // C/D: col = lane&15, row = (lane>>4)*4 + reg; gl pitch 17
#pragma unroll
        for (int r = 0; r < 4; ++r) {
            gl[(wave * 32 + qq * 4 + r) * 17 + r0] = acc0[r];
            gl[(wave * 32 + 16 + qq * 4 + r) * 17 + r0] = acc1[r];
        }
        __syncthreads();                          // S2

        // ---- epilogue: cell update; h stores (frag order) + out pre-S3 ----
#pragma unroll
        for (int it = 0; it < 2; ++it) {
            int bl = ebl0 + it * 16;
            int bb = b0 + bl;
            if (step < Lb[it]) {
                float gi = gl[(0 * 32 + bl) * 17 + ehl];
                float gj = gl[(1 * 32 + bl) * 17 + ehl];
                float gf = gl[(2 * 32 + bl) * 17 + ehl];
                float go = gl[(3 * 32 + bl) * 17 + ehl];
                float nc = c_reg[it] * sigmoidf_(gf) + sigmoidf_(gi) * tanhf_(gj);
                float nh = tanhf_(nc) * sigmoidf_(go);
                c_reg[it] = nc;
                h_reg[it] = f2b(nh);
                if (step == Lb[it] - 1)
                    h_final[((size_t)dir * NB + bb) * NH + hidx] = nh;
                int t_out = dir ? (Lb[it] - 1 - step) : step;
                out[((size_t)bb * NT + t_out) * (2 * NH) + dir * NH + hidx] = nh;
            } else {
                out[((size_t)bb * NT + step) * (2 * NH) + dir * NH + hidx] = 0.f;
            }
            __hip_atomic_store(&hout[eoff[it]], h_reg[it],
                               __ATOMIC_RELAXED, __HIP_MEMORY_SCOPE_AGENT);
        }

        __syncthreads();                          // S3: drain stores pre-arrive

        if (tid == 0)
            __hip_atomic_fetch_add(cnt, 1u, __ATOMIC_RELEASE, __HIP_MEMORY_SCOPE_WORKGROUP);

        // ---- step+1 x-part (hidden under barrier wait) ----
        if (mode == 2) gxload(step + 1); else xwindow(step + 1);

        if (tid == 0) {
            unsigned int tgt = 48u * (unsigned)(step + 1);
            while (__hip_atomic_load(cnt, __ATOMIC_RELAXED, __HIP_MEMORY_SCOPE_AGENT) < tgt)
                __builtin_amdgcn_s_sleep(2);
        }
        __syncthreads();                          // S4
    }
}

// ---------------- final hidden state (f32) -> d_out tail ----------------
__global__ __launch_bounds__(256) void write_state(const float* __restrict__ h_final,
                                                   float* __restrict__ out_state) {
    int i = blockIdx.x * 256 + threadIdx.x;      // over 2*NB*NH
    if (i < 2 * NB * NH) {
        int dir = i / (NB * NH);
        int rem = i - dir * (NB * NH);
        int b = rem / NH, h = rem - (rem / NH) * NH;
        out_state[(size_t)b * (2 * NH) + dir * NH + h] = h_final[i];
    }
}

extern "C" void kernel_launch(void* const* d_in, const int* in_sizes, int n_in,
                              void* d_out, int out_size, void* d_ws, size_t ws_size,
                              hipStream_t stream) {
    const float* seq   = (const float*)d_in[0];
    const int* seq_len = (const int*)d_in[1];
    const float* W_fw  = (const float*)d_in[2];
    const float* b_fw  = (const float*)d_in[3];
    const float* W_bw  = (const float*)d_in[4];
    const float* b_bw  = (const float*)d_in[5];
    float* out = (float*)d_out;

    char* ws = (char*)d_ws;
    size_t off = 0;
    unsigned short* WTf = (unsigned short*)(ws + off); off += (size_t)2 * NG * KTOT * 2; // 15,728,640
    unsigned short* hbufs = (unsigned short*)(ws + off);
    size_t hbuf_bytes = (size_t)3 * 2 * NB * NH * 2;   off += hbuf_bytes;                // 589,824
    float* h_final = (float*)(ws + off);
    size_t hf_bytes = (size_t)2 * NB * NH * 4;         off += hf_bytes;                  // 393,216
    unsigned int* barrier_cnts = (unsigned int*)(ws + off);
    size_t bar_bytes = 1024;                           off += bar_bytes;

    _Float16* Gx = (_Float16*)(ws + off);
    size_t gx_bytes = (size_t)2 * 512 * 196608 * 2;      // 402,653,184
    unsigned short* xbf = (unsigned short*)(ws + off);
    size_t xbf_bytes = (size_t)NB * NT * ND * 2;         // 33,554,432

    int mode = (ws_size >= off + gx_bytes) ? 2
             : ((ws_size >= off + xbf_bytes) ? 1 : 0);

    hipMemsetAsync(hbufs, 0, hbuf_bytes + hf_bytes + bar_bytes, stream);

    transpose_w<<<(KTOT / 64) * (NG / 64), 256, 0, stream>>>(W_fw, WTf);
    transpose_w<<<(KTOT / 64) * (NG / 64), 256, 0, stream>>>(W_bw, WTf + (size_t)NG * KTOT);

    if (mode == 2) {
        gemm_xw<<<1024, 256, 0, stream>>>(seq, WTf, b_fw, b_bw, Gx);
    } else if (mode == 1) {
        int n8 = NB * NT * ND / 8;
        convert_x<<<(n8 + 255) / 256, 256, 0, stream>>>(seq, xbf, n8);
    }

    size_t smem_bytes = 98304 + 8704;            // Whf (prologue) + gl
    lstm_persistent<<<192, 256, smem_bytes, stream>>>(
        seq, xbf, mode, seq_len, WTf, b_fw, b_bw, Gx,
        hbufs, h_final, out, barrier_cnts);

    write_state<<<(2 * NB * NH + 255) / 256, 256, 0, stream>>>(
        h_final, out + (size_t)NB * NT * 2 * NH);
}

// Round 7
// 3696.362 us; speedup vs baseline: 1.1087x; 1.0991x over previous
//
#include <hip/hip_runtime.h>

#define NB 64      // batch
#define NT 512     // time
#define ND 512     // input dim
#define NH 768     // hidden
#define KTOT 1280  // ND + NH
#define NG 3072    // 4*NH
#define NROW (NB * NT)  // 32768 rows of x
#define NHG 48          // h-groups (NH/16)
#define NCG 192         // col-groups (NG/16)
#define NKS 40          // k-slices (KTOT/32)

typedef short bf16x8 __attribute__((ext_vector_type(8)));
typedef float f32x4 __attribute__((ext_vector_type(4)));
typedef _Float16 f16x4 __attribute__((ext_vector_type(4)));

__device__ __forceinline__ unsigned short f2b(float f) {
    unsigned int u; __builtin_memcpy(&u, &f, 4);
    u = u + 0x7FFFu + ((u >> 16) & 1u);   // round-to-nearest-even
    return (unsigned short)(u >> 16);
}
__device__ __forceinline__ float sigmoidf_(float x) { return 1.f / (1.f + __expf(-x)); }
__device__ __forceinline__ float tanhf_(float x) { return 2.f / (1.f + __expf(-2.f * x)) - 1.f; }

// -------- W transpose+convert: W[KTOT][NG] f32 -> WTf fragment-ordered bf16 --------
// WTf[cg][ks][l][j] = W[ks*32 + (l>>4)*8 + j][cg*16 + (l&15)]
__global__ __launch_bounds__(256) void transpose_w(const float* __restrict__ W,
                                                   unsigned short* __restrict__ WTf) {
    __shared__ float tile[64][65];
    int bx = blockIdx.x % (NG / 64);   // col tile
    int by = blockIdx.x / (NG / 64);   // k tile
    int cb = bx * 64, kb = by * 64;
    int tid = threadIdx.x;
    {
        int r = tid >> 2;
        int coff = (tid & 3) * 16;
        const float* src = W + (size_t)(kb + r) * NG + cb + coff;
#pragma unroll
        for (int i = 0; i < 16; i += 4) {
            float4 v = *(const float4*)(src + i);
            tile[coff + i][r] = v.x; tile[coff + i + 1][r] = v.y;
            tile[coff + i + 2][r] = v.z; tile[coff + i + 3][r] = v.w;
        }
    }
    __syncthreads();
#pragma unroll
    for (int it = 0; it < 2; ++it) {
        int id = tid + it * 256;
        int ch = id >> 6;                 // 0..7
        int l = id & 63;
        int cgi = ch & 3, ksi = ch >> 2;
        int c = cgi * 16 + (l & 15);
        int k = ksi * 32 + ((l >> 4) * 8);
        bf16x8 o;
#pragma unroll
        for (int j = 0; j < 8; ++j) o[j] = (short)f2b(tile[c][k + j]);
        size_t cg = (size_t)(cb / 16) + cgi;
        size_t ks = (size_t)(kb / 32) + ksi;
        *(bf16x8*)(WTf + ((cg * NKS + ks) * 64 + l) * 8) = o;
    }
}

// -------- x f32 -> bf16 (mode 1 fallback) --------
__global__ __launch_bounds__(256) void convert_x(const float* __restrict__ src,
                                                 unsigned short* __restrict__ dst, int n8) {
    int i = blockIdx.x * 256 + threadIdx.x;
    if (i < n8) {
        const float4* s = (const float4*)(src + (size_t)i * 8);
        float4 v0 = s[0], v1 = s[1];
        bf16x8 o;
        o[0] = (short)f2b(v0.x); o[1] = (short)f2b(v0.y);
        o[2] = (short)f2b(v0.z); o[3] = (short)f2b(v0.w);
        o[4] = (short)f2b(v1.x); o[5] = (short)f2b(v1.y);
        o[6] = (short)f2b(v1.z); o[7] = (short)f2b(v1.w);
        *(bf16x8*)(dst + (size_t)i * 8) = o;
    }
}

// -------- precompute x-part gates (mode 2, f16 Gx, ~403MB) --------
// Gx layout = MFMA C-fragment natural order:
//   [dir][mblk(512)][nc(12)][gate(4)][nt(4)][m(4)][lane(64)][4] f16
__global__ __launch_bounds__(256) void gemm_xw(
    const float* __restrict__ seq,
    const unsigned short* __restrict__ WTf,
    const float* __restrict__ b_fw,
    const float* __restrict__ b_bw,
    _Float16* __restrict__ Gx) {
    __shared__ unsigned short Albs[64 * 522];    // odd dword pitch -> <=2-way
    int blk = blockIdx.x;
    int dir = blk >> 9;
    int mbi = blk & 511;
    int mb = mbi * 64;
    const float* bias = dir ? b_bw : b_fw;
    int tid = threadIdx.x;
    {
        int r = tid >> 2;
        int c = tid & 3;
        const float* src = seq + (size_t)(mb + r) * ND;
#pragma unroll
        for (int i = 0; i < 16; ++i) {
            int k = c * 8 + i * 32;
            float4 v0 = *(const float4*)(src + k);
            float4 v1 = *(const float4*)(src + k + 4);
            bf16x8 o;
            o[0] = (short)f2b(v0.x); o[1] = (short)f2b(v0.y);
            o[2] = (short)f2b(v0.z); o[3] = (short)f2b(v0.w);
            o[4] = (short)f2b(v1.x); o[5] = (short)f2b(v1.y);
            o[6] = (short)f2b(v1.z); o[7] = (short)f2b(v1.w);
            *(bf16x8*)&Albs[r * 522 + k] = o;
        }
    }
    __syncthreads();
    int lane = tid & 63, wave = tid >> 6;
    int r0 = lane & 15, qq = lane >> 4, q8 = qq * 8;
    _Float16* gbase = Gx + (size_t)(dir * 512 + mbi) * 196608;
#pragma unroll 1
    for (int nc = 0; nc < 12; ++nc) {
        int colbase = wave * NH + nc * 64;       // gate == wave
        f32x4 acc[4][4];
#pragma unroll
        for (int nt = 0; nt < 4; ++nt) {
            float bv = bias[colbase + nt * 16 + r0] + (wave == 2 ? 1.0f : 0.0f);
#pragma unroll
            for (int m = 0; m < 4; ++m) {
                acc[m][nt][0] = bv; acc[m][nt][1] = bv;
                acc[m][nt][2] = bv; acc[m][nt][3] = bv;
            }
        }
        const unsigned short* fpre = WTf +
            ((size_t)(dir * NCG + wave * NHG + nc * 4) * NKS) * 512 + (size_t)lane * 8;
#pragma unroll
        for (int ks = 0; ks < 16; ++ks) {
            bf16x8 a[4], bb[4];
#pragma unroll
            for (int m = 0; m < 4; ++m)
                a[m] = *(const bf16x8*)&Albs[(m * 16 + r0) * 522 + ks * 32 + q8];
#pragma unroll
            for (int nt = 0; nt < 4; ++nt)
                bb[nt] = *(const bf16x8*)(fpre + ((size_t)nt * NKS + ks) * 512);
#pragma unroll
            for (int m = 0; m < 4; ++m)
#pragma unroll
                for (int nt = 0; nt < 4; ++nt)
                    acc[m][nt] = __builtin_amdgcn_mfma_f32_16x16x32_bf16(a[m], bb[nt], acc[m][nt], 0, 0, 0);
        }
#pragma unroll
        for (int nt = 0; nt < 4; ++nt) {
#pragma unroll
            for (int m = 0; m < 4; ++m) {
                f16x4 o;
                o[0] = (_Float16)acc[m][nt][0]; o[1] = (_Float16)acc[m][nt][1];
                o[2] = (_Float16)acc[m][nt][2]; o[3] = (_Float16)acc[m][nt][3];
                *(f16x4*)(gbase + (size_t)((((nc * 4 + wave) * 4 + nt) * 4 + m) * 64 + lane) * 4) = o;
            }
        }
    }
}

// ---------------- persistent bidirectional LSTM ----------------
// Round 7: wave-autonomous slices, zero in-loop barriers.
// 192 blocks x 128 threads = 384 waves; wave = (dir, bgroup, hgroup, rowhalf):
// 16 rows x (4 gates x 16 h-dims), K=768. Block = 2 rowhalf-waves sharing only
// read-only Whf (64 cols x 768 = 96KB LDS, fragment order).
//  * A-fragments (own 16 rows of h) loaded sc1 direct to registers, 4 chunks
//    of 6 ks, 2 in flight. No duplication (rows are wave-private).
//  * C-fragment holds all 4 gates per lane -> lane-local cell update, no LDS
//    gate bounce, no __syncthreads anywhere in the loop.
//  * Arrival: per-wave lane0 {s_waitcnt vmcnt(0); relaxed add}; target 96
//    waves per (dir,bgroup) group. Poll: per-wave lane0 spin. Skew across
//    waves bounded to 1 step; 3-buffer h rotation tolerates it.
//  * out/h_final stores post-arrive (drain hides under next step's chain).
// Accumulation order per output unchanged (Gx init -> h ks ascending) =>
// bitwise-identical to rounds 4/6 (absmax 0.00390625 expected).
__global__ __launch_bounds__(128, 1) void lstm_persistent(
    const float* __restrict__ seq,
    const unsigned short* __restrict__ xbf,
    int mode,                                    // 0: x f32, 1: x bf16, 2: Gx f16
    const int* __restrict__ seq_len,
    const unsigned short* __restrict__ WTf,      // fragment-ordered
    const float* __restrict__ bias_fw,
    const float* __restrict__ bias_bw,
    const _Float16* __restrict__ Gx,             // mode 2
    unsigned short* __restrict__ hbufs,          // [3][2][4][24][64][8] bf16 (frag order)
    float* __restrict__ h_final,                 // [2][NB][NH] f32
    float* __restrict__ out,                     // [NB][NT][2*NH] f32
    unsigned int* __restrict__ barrier_cnts)     // 4 counters, 256B apart
{
    extern __shared__ char smem[];
    unsigned short* Whf = (unsigned short*)smem; // [4 gates][24 ks][64 lanes][8] = 96KB

    int bid = blockIdx.x;
    int hgroup = bid % NHG;
    int bgroup = (bid / NHG) & 1;
    int dir = bid / (2 * NHG);
    int grp = bid / NHG;                         // barrier group 0..3
    int b0 = bgroup * 32;
    int hbase = hgroup * 16;
    int tid = threadIdx.x;                       // 0..127
    int lane = tid & 63;
    int rh = tid >> 6;                           // wave = row half
    int r0 = lane & 15;
    int qq = lane >> 4;

    const float* bias = dir ? bias_bw : bias_fw;
    int hidx = hbase + r0;

    // ---- fill Whf (fragment order): chunk c = gate*24 + ks, 1KB each ----
#pragma unroll
    for (int i = 0; i < 48; ++i) {
        int c = i * 2 + rh;
        int g = c / 24, ks = c - g * 24;
        const unsigned short* src = WTf +
            ((size_t)(dir * NCG + g * NHG + hgroup) * NKS + 16 + ks) * 512 + (size_t)lane * 8;
        *(bf16x8*)(Whf + ((size_t)c * 64 + lane) * 8) = *(const bf16x8*)src;
    }

    // ---- per-lane geometry: 4 rows (C-frag regs), 1 h-col ----
    int rows[4], L[4];
#pragma unroll
    for (int e = 0; e < 4; ++e) {
        rows[e] = b0 + rh * 16 + qq * 4 + e;
        L[e] = seq_len[rows[e]];
    }
    float bvg[4];
#pragma unroll
    for (int g = 0; g < 4; ++g) bvg[g] = bias[g * NH + hidx] + (g == 2 ? 1.0f : 0.0f);

    float c_reg[4] = {0.f, 0.f, 0.f, 0.f};
    unsigned short h_reg[4] = {0, 0, 0, 0};
    size_t eoff[4];                              // frag-order h-store offsets
#pragma unroll
    for (int e = 0; e < 4; ++e) {
        int bb = rows[e];
        eoff[e] = ((size_t)((bb >> 4) * 24 + (hidx >> 5)) * 64 +
                   (size_t)(((hidx >> 3) & 3) * 16 + (bb & 15))) * 8 + (hidx & 7);
    }

    // ---- x-part state ----
    float gxv[16];                               // [g*4+e], mode 2
    size_t gK[4];
    if (mode == 2) {
#pragma unroll
        for (int g = 0; g < 4; ++g)
            gK[g] = (size_t)dir * 100663296 + (size_t)(hgroup >> 2) * 16384 +
                    (size_t)g * 4096 + (size_t)(hgroup & 3) * 1024 + (size_t)r0 * 4;
    }
    auto gxload = [&](int stepn) {
#pragma unroll
        for (int e = 0; e < 4; ++e) {
            int tn = dir ? (L[e] - 1 - stepn) : stepn;
            tn = tn < 0 ? 0 : (tn > NT - 1 ? NT - 1 : tn);
            int R = rows[e] * NT + tn;
            size_t ra = (size_t)(R >> 6) * 196608 +
                        (size_t)(((R >> 4) & 3) * 256 + ((R >> 2) & 3) * 64 + (R & 3));
#pragma unroll
            for (int g = 0; g < 4; ++g) gxv[g * 4 + e] = (float)Gx[gK[g] + ra];
        }
    };

    // modes 0/1 fallback: per-wave x-GEMM (A from global, Wx B-frags from WTf/L2)
    f32x4 ax[4];
    int rowA = b0 + rh * 16 + r0;                // this lane's A-frag row
    int LA = seq_len[rowA];
    auto xwindow = [&](int stepn) {
#pragma unroll
        for (int g = 0; g < 4; ++g) {
            ax[g][0] = bvg[g]; ax[g][1] = bvg[g]; ax[g][2] = bvg[g]; ax[g][3] = bvg[g];
        }
        int tn = dir ? (LA - 1 - stepn) : stepn;
        tn = tn < 0 ? 0 : (tn > NT - 1 ? NT - 1 : tn);
#pragma unroll
        for (int ks = 0; ks < 16; ++ks) {
            bf16x8 av;
            if (mode == 1) {
                av = *(const bf16x8*)(xbf + ((size_t)rowA * NT + tn) * ND + ks * 32 + qq * 8);
            } else {
                const float* xr = seq + ((size_t)rowA * NT + tn) * ND + ks * 32 + qq * 8;
                float4 v0 = *(const float4*)xr, v1 = *(const float4*)(xr + 4);
                av[0] = (short)f2b(v0.x); av[1] = (short)f2b(v0.y);
                av[2] = (short)f2b(v0.z); av[3] = (short)f2b(v0.w);
                av[4] = (short)f2b(v1.x); av[5] = (short)f2b(v1.y);
                av[6] = (short)f2b(v1.z); av[7] = (short)f2b(v1.w);
            }
#pragma unroll
            for (int g = 0; g < 4; ++g) {
                bf16x8 bx = *(const bf16x8*)(WTf +
                    ((size_t)(dir * NCG + g * NHG + hgroup) * NKS + ks) * 512 + (size_t)lane * 8);
                ax[g] = __builtin_amdgcn_mfma_f32_16x16x32_bf16(av, bx, ax[g], 0, 0, 0);
            }
        }
    };

    if (mode == 2) gxload(0); else xwindow(0);
    __syncthreads();                             // Whf ready (only barrier in kernel)

    unsigned int* cnt = barrier_cnts + grp * 64; // 256B apart
    int rb = bgroup * 2 + rh;                    // this wave's h row-block (16 rows)

    for (int step = 0; step < NT; ++step) {
        const unsigned long long* hin64 = (const unsigned long long*)
            (hbufs + (size_t)(step % 3) * (2 * NB * NH) + (size_t)dir * NB * NH);
        unsigned short* hout = hbufs + (size_t)((step + 1) % 3) * (2 * NB * NH) + (size_t)dir * NB * NH;

        // ---- h A-fragments: wave-private sc1 loads, 4 chunks of 6 ks, 2 in flight ----
        unsigned long long huA[12], huB[12];
        auto issue = [&](int c, unsigned long long* hu) {
#pragma unroll
            for (int i = 0; i < 6; ++i) {
                int ks = c * 6 + i;
                size_t o = ((size_t)(rb * 24 + ks) * 64 + lane) * 2;
                hu[2 * i]     = __hip_atomic_load(hin64 + o,     __ATOMIC_RELAXED, __HIP_MEMORY_SCOPE_AGENT);
                hu[2 * i + 1] = __hip_atomic_load(hin64 + o + 1, __ATOMIC_RELAXED, __HIP_MEMORY_SCOPE_AGENT);
            }
        };

        f32x4 acc[4];
        if (mode == 2) {
#pragma unroll
            for (int g = 0; g < 4; ++g) {
                acc[g][0] = gxv[g * 4 + 0]; acc[g][1] = gxv[g * 4 + 1];
                acc[g][2] = gxv[g * 4 + 2]; acc[g][3] = gxv[g * 4 + 3];
            }
        } else {
#pragma unroll
            for (int g = 0; g < 4; ++g) acc[g] = ax[g];
        }

        const unsigned short* wf = Whf + (size_t)lane * 8;
        auto consume = [&](int c, const unsigned long long* hu) {
#pragma unroll
            for (int i = 0; i < 6; ++i) {
                int ks = c * 6 + i;
                union { unsigned long long u[2]; bf16x8 v; } fa;
                fa.u[0] = hu[2 * i]; fa.u[1] = hu[2 * i + 1];
#pragma unroll
                for (int g = 0; g < 4; ++g) {
                    bf16x8 wb = *(const bf16x8*)(wf + (size_t)(g * 24 + ks) * 512);
                    acc[g] = __builtin_amdgcn_mfma_f32_16x16x32_bf16(fa.v, wb, acc[g], 0, 0, 0);
                }
            }
        };

        issue(0, huA);
        issue(1, huB);
        consume(0, huA); issue(2, huA);
        consume(1, huB); issue(3, huB);
        consume(2, huA);
        consume(3, huB);

        // ---- lane-local cell update (all 4 gates in acc[g][e]) ----
        float nhv[4] = {0.f, 0.f, 0.f, 0.f};
#pragma unroll
        for (int e = 0; e < 4; ++e) {
            if (step < L[e]) {
                float gi = acc[0][e], gj = acc[1][e], gf = acc[2][e], go = acc[3][e];
                float nc = c_reg[e] * sigmoidf_(gf) + sigmoidf_(gi) * tanhf_(gj);
                float nh = tanhf_(nc) * sigmoidf_(go);
                c_reg[e] = nc;
                h_reg[e] = f2b(nh);
                nhv[e] = nh;
            }
            __hip_atomic_store(&hout[eoff[e]], h_reg[e],
                               __ATOMIC_RELAXED, __HIP_MEMORY_SCOPE_AGENT);
        }

        // ---- per-wave arrive: drain own stores, then count ----
        asm volatile("s_waitcnt vmcnt(0)" ::: "memory");
        if (lane == 0)
            __hip_atomic_fetch_add(cnt, 1u, __ATOMIC_RELEASE, __HIP_MEMORY_SCOPE_WORKGROUP);

        // ---- post-arrive: prefetch + output stores (hidden under poll) ----
        if (mode == 2) gxload(step + 1); else xwindow(step + 1);
#pragma unroll
        for (int e = 0; e < 4; ++e) {
            int bb = rows[e];
            if (step < L[e]) {
                int t_out = dir ? (L[e] - 1 - step) : step;
                out[((size_t)bb * NT + t_out) * (2 * NH) + dir * NH + hidx] = nhv[e];
                if (step == L[e] - 1)
                    h_final[((size_t)dir * NB + bb) * NH + hidx] = nhv[e];
            } else {
                out[((size_t)bb * NT + step) * (2 * NH) + dir * NH + hidx] = 0.f;
            }
        }

        // ---- per-wave poll ----
        {
            unsigned int tgt = 96u * (unsigned)(step + 1);
            if (lane == 0) {
                while (__hip_atomic_load(cnt, __ATOMIC_RELAXED, __HIP_MEMORY_SCOPE_AGENT) < tgt)
                    __builtin_amdgcn_s_sleep(2);
            }
        }
        __builtin_amdgcn_sched_barrier(0);       // no load hoisting above the poll
        asm volatile("" ::: "memory");
    }
}

// ---------------- final hidden state (f32) -> d_out tail ----------------
__global__ __launch_bounds__(256) void write_state(const float* __restrict__ h_final,
                                                   float* __restrict__ out_state) {
    int i = blockIdx.x * 256 + threadIdx.x;      // over 2*NB*NH
    if (i < 2 * NB * NH) {
        int dir = i / (NB * NH);
        int rem = i - dir * (NB * NH);
        int b = rem / NH, h = rem - (rem / NH) * NH;
        out_state[(size_t)b * (2 * NH) + dir * NH + h] = h_final[i];
    }
}

extern "C" void kernel_launch(void* const* d_in, const int* in_sizes, int n_in,
                              void* d_out, int out_size, void* d_ws, size_t ws_size,
                              hipStream_t stream) {
    const float* seq   = (const float*)d_in[0];
    const int* seq_len = (const int*)d_in[1];
    const float* W_fw  = (const float*)d_in[2];
    const float* b_fw  = (const float*)d_in[3];
    const float* W_bw  = (const float*)d_in[4];
    const float* b_bw  = (const float*)d_in[5];
    float* out = (float*)d_out;

    char* ws = (char*)d_ws;
    size_t off = 0;
    unsigned short* WTf = (unsigned short*)(ws + off); off += (size_t)2 * NG * KTOT * 2; // 15,728,640
    unsigned short* hbufs = (unsigned short*)(ws + off);
    size_t hbuf_bytes = (size_t)3 * 2 * NB * NH * 2;   off += hbuf_bytes;                // 589,824
    float* h_final = (float*)(ws + off);
    size_t hf_bytes = (size_t)2 * NB * NH * 4;         off += hf_bytes;                  // 393,216
    unsigned int* barrier_cnts = (unsigned int*)(ws + off);
    size_t bar_bytes = 1024;                           off += bar_bytes;

    _Float16* Gx = (_Float16*)(ws + off);
    size_t gx_bytes = (size_t)2 * 512 * 196608 * 2;      // 402,653,184
    unsigned short* xbf = (unsigned short*)(ws + off);
    size_t xbf_bytes = (size_t)NB * NT * ND * 2;         // 33,554,432

    int mode = (ws_size >= off + gx_bytes) ? 2
             : ((ws_size >= off + xbf_bytes) ? 1 : 0);

    hipMemsetAsync(hbufs, 0, hbuf_bytes + hf_bytes + bar_bytes, stream);

    transpose_w<<<(KTOT / 64) * (NG / 64), 256, 0, stream>>>(W_fw, WTf);
    transpose_w<<<(KTOT / 64) * (NG / 64), 256, 0, stream>>>(W_bw, WTf + (size_t)NG * KTOT);

    if (mode == 2) {
        gemm_xw<<<1024, 256, 0, stream>>>(seq, WTf, b_fw, b_bw, Gx);
    } else if (mode == 1) {
        int n8 = NB * NT * ND / 8;
        convert_x<<<(n8 + 255) / 256, 256, 0, stream>>>(seq, xbf, n8);
    }

    size_t smem_bytes = 98304;                   // Whf only
    lstm_persistent<<<192, 128, smem_bytes, stream>>>(
        seq, xbf, mode, seq_len, WTf, b_fw, b_bw, Gx,
        hbufs, h_final, out, barrier_cnts);

    write_state<<<(2 * NB * NH + 255) / 256, 256, 0, stream>>>(
        h_final, out + (size_t)NB * NT * 2 * NH);
}

// Round 8
// 3434.840 us; speedup vs baseline: 1.1931x; 1.0761x over previous
//
#include <hip/hip_runtime.h>

#define NB 64      // batch
#define NT 512     // time
#define ND 512     // input dim
#define NH 768     // hidden
#define KTOT 1280  // ND + NH
#define NG 3072    // 4*NH
#define NROW (NB * NT)  // 32768 rows of x
#define NHG 48          // h-groups (NH/16)
#define NCG 192         // col-groups (NG/16)
#define NKS 40          // k-slices (KTOT/32)

typedef short bf16x8 __attribute__((ext_vector_type(8)));
typedef float f32x4 __attribute__((ext_vector_type(4)));
typedef _Float16 f16x4 __attribute__((ext_vector_type(4)));

__device__ __forceinline__ unsigned short f2b(float f) {
    unsigned int u; __builtin_memcpy(&u, &f, 4);
    u = u + 0x7FFFu + ((u >> 16) & 1u);   // round-to-nearest-even
    return (unsigned short)(u >> 16);
}
__device__ __forceinline__ float sigmoidf_(float x) { return 1.f / (1.f + __expf(-x)); }
__device__ __forceinline__ float tanhf_(float x) { return 2.f / (1.f + __expf(-2.f * x)) - 1.f; }

// -------- W transpose+convert: W[KTOT][NG] f32 -> WTf fragment-ordered bf16 --------
// WTf[cg][ks][l][j] = W[ks*32 + (l>>4)*8 + j][cg*16 + (l&15)]
__global__ __launch_bounds__(256) void transpose_w(const float* __restrict__ W,
                                                   unsigned short* __restrict__ WTf) {
    __shared__ float tile[64][65];
    int bx = blockIdx.x % (NG / 64);   // col tile
    int by = blockIdx.x / (NG / 64);   // k tile
    int cb = bx * 64, kb = by * 64;
    int tid = threadIdx.x;
    {
        int r = tid >> 2;
        int coff = (tid & 3) * 16;
        const float* src = W + (size_t)(kb + r) * NG + cb + coff;
#pragma unroll
        for (int i = 0; i < 16; i += 4) {
            float4 v = *(const float4*)(src + i);
            tile[coff + i][r] = v.x; tile[coff + i + 1][r] = v.y;
            tile[coff + i + 2][r] = v.z; tile[coff + i + 3][r] = v.w;
        }
    }
    __syncthreads();
#pragma unroll
    for (int it = 0; it < 2; ++it) {
        int id = tid + it * 256;
        int ch = id >> 6;                 // 0..7
        int l = id & 63;
        int cgi = ch & 3, ksi = ch >> 2;
        int c = cgi * 16 + (l & 15);
        int k = ksi * 32 + ((l >> 4) * 8);
        bf16x8 o;
#pragma unroll
        for (int j = 0; j < 8; ++j) o[j] = (short)f2b(tile[c][k + j]);
        size_t cg = (size_t)(cb / 16) + cgi;
        size_t ks = (size_t)(kb / 32) + ksi;
        *(bf16x8*)(WTf + ((cg * NKS + ks) * 64 + l) * 8) = o;
    }
}

// -------- x f32 -> bf16 (mode 1 fallback) --------
__global__ __launch_bounds__(256) void convert_x(const float* __restrict__ src,
                                                 unsigned short* __restrict__ dst, int n8) {
    int i = blockIdx.x * 256 + threadIdx.x;
    if (i < n8) {
        const float4* s = (const float4*)(src + (size_t)i * 8);
        float4 v0 = s[0], v1 = s[1];
        bf16x8 o;
        o[0] = (short)f2b(v0.x); o[1] = (short)f2b(v0.y);
        o[2] = (short)f2b(v0.z); o[3] = (short)f2b(v0.w);
        o[4] = (short)f2b(v1.x); o[5] = (short)f2b(v1.y);
        o[6] = (short)f2b(v1.z); o[7] = (short)f2b(v1.w);
        *(bf16x8*)(dst + (size_t)i * 8) = o;
    }
}

// -------- precompute x-part gates (mode 2, f16 Gx, ~403MB) --------
// Gx layout = MFMA C-fragment natural order:
//   [dir][mblk(512)][nc(12)][gate(4)][nt(4)][m(4)][lane(64)][4] f16
__global__ __launch_bounds__(256) void gemm_xw(
    const float* __restrict__ seq,
    const unsigned short* __restrict__ WTf,
    const float* __restrict__ b_fw,
    const float* __restrict__ b_bw,
    _Float16* __restrict__ Gx) {
    __shared__ unsigned short Albs[64 * 522];    // odd dword pitch -> <=2-way
    int blk = blockIdx.x;
    int dir = blk >> 9;
    int mbi = blk & 511;
    int mb = mbi * 64;
    const float* bias = dir ? b_bw : b_fw;
    int tid = threadIdx.x;
    {
        int r = tid >> 2;
        int c = tid & 3;
        const float* src = seq + (size_t)(mb + r) * ND;
#pragma unroll
        for (int i = 0; i < 16; ++i) {
            int k = c * 8 + i * 32;
            float4 v0 = *(const float4*)(src + k);
            float4 v1 = *(const float4*)(src + k + 4);
            bf16x8 o;
            o[0] = (short)f2b(v0.x); o[1] = (short)f2b(v0.y);
            o[2] = (short)f2b(v0.z); o[3] = (short)f2b(v0.w);
            o[4] = (short)f2b(v1.x); o[5] = (short)f2b(v1.y);
            o[6] = (short)f2b(v1.z); o[7] = (short)f2b(v1.w);
            *(bf16x8*)&Albs[r * 522 + k] = o;
        }
    }
    __syncthreads();
    int lane = tid & 63, wave = tid >> 6;
    int r0 = lane & 15, qq = lane >> 4, q8 = qq * 8;
    _Float16* gbase = Gx + (size_t)(dir * 512 + mbi) * 196608;
#pragma unroll 1
    for (int nc = 0; nc < 12; ++nc) {
        int colbase = wave * NH + nc * 64;       // gate == wave
        f32x4 acc[4][4];
#pragma unroll
        for (int nt = 0; nt < 4; ++nt) {
            float bv = bias[colbase + nt * 16 + r0] + (wave == 2 ? 1.0f : 0.0f);
#pragma unroll
            for (int m = 0; m < 4; ++m) {
                acc[m][nt][0] = bv; acc[m][nt][1] = bv;
                acc[m][nt][2] = bv; acc[m][nt][3] = bv;
            }
        }
        const unsigned short* fpre = WTf +
            ((size_t)(dir * NCG + wave * NHG + nc * 4) * NKS) * 512 + (size_t)lane * 8;
#pragma unroll
        for (int ks = 0; ks < 16; ++ks) {
            bf16x8 a[4], bb[4];
#pragma unroll
            for (int m = 0; m < 4; ++m)
                a[m] = *(const bf16x8*)&Albs[(m * 16 + r0) * 522 + ks * 32 + q8];
#pragma unroll
            for (int nt = 0; nt < 4; ++nt)
                bb[nt] = *(const bf16x8*)(fpre + ((size_t)nt * NKS + ks) * 512);
#pragma unroll
            for (int m = 0; m < 4; ++m)
#pragma unroll
                for (int nt = 0; nt < 4; ++nt)
                    acc[m][nt] = __builtin_amdgcn_mfma_f32_16x16x32_bf16(a[m], bb[nt], acc[m][nt], 0, 0, 0);
        }
#pragma unroll
        for (int nt = 0; nt < 4; ++nt) {
#pragma unroll
            for (int m = 0; m < 4; ++m) {
                f16x4 o;
                o[0] = (_Float16)acc[m][nt][0]; o[1] = (_Float16)acc[m][nt][1];
                o[2] = (_Float16)acc[m][nt][2]; o[3] = (_Float16)acc[m][nt][3];
                *(f16x4*)(gbase + (size_t)((((nc * 4 + wave) * 4 + nt) * 4 + m) * 64 + lane) * 4) = o;
            }
        }
    }
}

// ---------------- persistent bidirectional LSTM ----------------
// Round 8 = round 7 with ONE change: the group barrier's shared atomic counter
// (48-96 serialized RMWs on one L3 line per step -- the suspected 5.6us/step
// floor) is replaced by per-wave FLAG LINES:
//  * arrive: s_waitcnt vmcnt(0) (h stores acked at L3), then lane0 plain
//    sc1-stores step+1 to this wave's private 64B flag line. No RMW.
//  * poll: all 64 lanes in parallel read the group's 96 flags (lane l reads
//    flag[l] and flag[64+(l&31)]), exit on __all(>= step+1). Flag visible =>
//    that wave's h data visible (it drained before flagging).
// Everything else identical to round 7 (numerics bitwise-identical).
__global__ __launch_bounds__(128, 1) void lstm_persistent(
    const float* __restrict__ seq,
    const unsigned short* __restrict__ xbf,
    int mode,                                    // 0: x f32, 1: x bf16, 2: Gx f16
    const int* __restrict__ seq_len,
    const unsigned short* __restrict__ WTf,      // fragment-ordered
    const float* __restrict__ bias_fw,
    const float* __restrict__ bias_bw,
    const _Float16* __restrict__ Gx,             // mode 2
    unsigned short* __restrict__ hbufs,          // [3][2][4][24][64][8] bf16 (frag order)
    float* __restrict__ h_final,                 // [2][NB][NH] f32
    float* __restrict__ out,                     // [NB][NT][2*NH] f32
    unsigned int* __restrict__ flags)            // [4 groups][96 waves] x 64B lines
{
    extern __shared__ char smem[];
    unsigned short* Whf = (unsigned short*)smem; // [4 gates][24 ks][64 lanes][8] = 96KB

    int bid = blockIdx.x;
    int hgroup = bid % NHG;
    int bgroup = (bid / NHG) & 1;
    int dir = bid / (2 * NHG);
    int grp = bid / NHG;                         // barrier group 0..3
    int b0 = bgroup * 32;
    int hbase = hgroup * 16;
    int tid = threadIdx.x;                       // 0..127
    int lane = tid & 63;
    int rh = tid >> 6;                           // wave = row half
    int r0 = lane & 15;
    int qq = lane >> 4;

    const float* bias = dir ? bias_bw : bias_fw;
    int hidx = hbase + r0;

    // ---- fill Whf (fragment order): chunk c = gate*24 + ks, 1KB each ----
#pragma unroll
    for (int i = 0; i < 48; ++i) {
        int c = i * 2 + rh;
        int g = c / 24, ks = c - g * 24;
        const unsigned short* src = WTf +
            ((size_t)(dir * NCG + g * NHG + hgroup) * NKS + 16 + ks) * 512 + (size_t)lane * 8;
        *(bf16x8*)(Whf + ((size_t)c * 64 + lane) * 8) = *(const bf16x8*)src;
    }

    // ---- per-lane geometry: 4 rows (C-frag regs), 1 h-col ----
    int rows[4], L[4];
#pragma unroll
    for (int e = 0; e < 4; ++e) {
        rows[e] = b0 + rh * 16 + qq * 4 + e;
        L[e] = seq_len[rows[e]];
    }
    float bvg[4];
#pragma unroll
    for (int g = 0; g < 4; ++g) bvg[g] = bias[g * NH + hidx] + (g == 2 ? 1.0f : 0.0f);

    float c_reg[4] = {0.f, 0.f, 0.f, 0.f};
    unsigned short h_reg[4] = {0, 0, 0, 0};
    size_t eoff[4];                              // frag-order h-store offsets
#pragma unroll
    for (int e = 0; e < 4; ++e) {
        int bb = rows[e];
        eoff[e] = ((size_t)((bb >> 4) * 24 + (hidx >> 5)) * 64 +
                   (size_t)(((hidx >> 3) & 3) * 16 + (bb & 15))) * 8 + (hidx & 7);
    }

    // ---- flag pointers (per-wave line = 16 u32 = 64B) ----
    unsigned int* myflag = flags + ((size_t)grp * 96 + (size_t)hgroup * 2 + rh) * 16;
    const unsigned int* f1p = flags + ((size_t)grp * 96 + lane) * 16;
    const unsigned int* f2p = flags + ((size_t)grp * 96 + 64 + (lane & 31)) * 16;

    // ---- x-part state ----
    float gxv[16];                               // [g*4+e], mode 2
    size_t gK[4];
    if (mode == 2) {
#pragma unroll
        for (int g = 0; g < 4; ++g)
            gK[g] = (size_t)dir * 100663296 + (size_t)(hgroup >> 2) * 16384 +
                    (size_t)g * 4096 + (size_t)(hgroup & 3) * 1024 + (size_t)r0 * 4;
    }
    auto gxload = [&](int stepn) {
#pragma unroll
        for (int e = 0; e < 4; ++e) {
            int tn = dir ? (L[e] - 1 - stepn) : stepn;
            tn = tn < 0 ? 0 : (tn > NT - 1 ? NT - 1 : tn);
            int R = rows[e] * NT + tn;
            size_t ra = (size_t)(R >> 6) * 196608 +
                        (size_t)(((R >> 4) & 3) * 256 + ((R >> 2) & 3) * 64 + (R & 3));
#pragma unroll
            for (int g = 0; g < 4; ++g) gxv[g * 4 + e] = (float)Gx[gK[g] + ra];
        }
    };

    // modes 0/1 fallback: per-wave x-GEMM (A from global, Wx B-frags from WTf/L2)
    f32x4 ax[4];
    int rowA = b0 + rh * 16 + r0;                // this lane's A-frag row
    int LA = seq_len[rowA];
    auto xwindow = [&](int stepn) {
#pragma unroll
        for (int g = 0; g < 4; ++g) {
            ax[g][0] = bvg[g]; ax[g][1] = bvg[g]; ax[g][2] = bvg[g]; ax[g][3] = bvg[g];
        }
        int tn = dir ? (LA - 1 - stepn) : stepn;
        tn = tn < 0 ? 0 : (tn > NT - 1 ? NT - 1 : tn);
#pragma unroll
        for (int ks = 0; ks < 16; ++ks) {
            bf16x8 av;
            if (mode == 1) {
                av = *(const bf16x8*)(xbf + ((size_t)rowA * NT + tn) * ND + ks * 32 + qq * 8);
            } else {
                const float* xr = seq + ((size_t)rowA * NT + tn) * ND + ks * 32 + qq * 8;
                float4 v0 = *(const float4*)xr, v1 = *(const float4*)(xr + 4);
                av[0] = (short)f2b(v0.x); av[1] = (short)f2b(v0.y);
                av[2] = (short)f2b(v0.z); av[3] = (short)f2b(v0.w);
                av[4] = (short)f2b(v1.x); av[5] = (short)f2b(v1.y);
                av[6] = (short)f2b(v1.z); av[7] = (short)f2b(v1.w);
            }
#pragma unroll
            for (int g = 0; g < 4; ++g) {
                bf16x8 bx = *(const bf16x8*)(WTf +
                    ((size_t)(dir * NCG + g * NHG + hgroup) * NKS + ks) * 512 + (size_t)lane * 8);
                ax[g] = __builtin_amdgcn_mfma_f32_16x16x32_bf16(av, bx, ax[g], 0, 0, 0);
            }
        }
    };

    if (mode == 2) gxload(0); else xwindow(0);
    __syncthreads();                             // Whf ready (only barrier in kernel)

    int rb = bgroup * 2 + rh;                    // this wave's h row-block (16 rows)

    for (int step = 0; step < NT; ++step) {
        const unsigned long long* hin64 = (const unsigned long long*)
            (hbufs + (size_t)(step % 3) * (2 * NB * NH) + (size_t)dir * NB * NH);
        unsigned short* hout = hbufs + (size_t)((step + 1) % 3) * (2 * NB * NH) + (size_t)dir * NB * NH;

        // ---- h A-fragments: wave-private sc1 loads, 4 chunks of 6 ks, 2 in flight ----
        unsigned long long huA[12], huB[12];
        auto issue = [&](int c, unsigned long long* hu) {
#pragma unroll
            for (int i = 0; i < 6; ++i) {
                int ks = c * 6 + i;
                size_t o = ((size_t)(rb * 24 + ks) * 64 + lane) * 2;
                hu[2 * i]     = __hip_atomic_load(hin64 + o,     __ATOMIC_RELAXED, __HIP_MEMORY_SCOPE_AGENT);
                hu[2 * i + 1] = __hip_atomic_load(hin64 + o + 1, __ATOMIC_RELAXED, __HIP_MEMORY_SCOPE_AGENT);
            }
        };

        f32x4 acc[4];
        if (mode == 2) {
#pragma unroll
            for (int g = 0; g < 4; ++g) {
                acc[g][0] = gxv[g * 4 + 0]; acc[g][1] = gxv[g * 4 + 1];
                acc[g][2] = gxv[g * 4 + 2]; acc[g][3] = gxv[g * 4 + 3];
            }
        } else {
#pragma unroll
            for (int g = 0; g < 4; ++g) acc[g] = ax[g];
        }

        const unsigned short* wf = Whf + (size_t)lane * 8;
        auto consume = [&](int c, const unsigned long long* hu) {
#pragma unroll
            for (int i = 0; i < 6; ++i) {
                int ks = c * 6 + i;
                union { unsigned long long u[2]; bf16x8 v; } fa;
                fa.u[0] = hu[2 * i]; fa.u[1] = hu[2 * i + 1];
#pragma unroll
                for (int g = 0; g < 4; ++g) {
                    bf16x8 wb = *(const bf16x8*)(wf + (size_t)(g * 24 + ks) * 512);
                    acc[g] = __builtin_amdgcn_mfma_f32_16x16x32_bf16(fa.v, wb, acc[g], 0, 0, 0);
                }
            }
        };

        issue(0, huA);
        issue(1, huB);
        consume(0, huA); issue(2, huA);
        consume(1, huB); issue(3, huB);
        consume(2, huA);
        consume(3, huB);

        // ---- lane-local cell update (all 4 gates in acc[g][e]) ----
        float nhv[4] = {0.f, 0.f, 0.f, 0.f};
#pragma unroll
        for (int e = 0; e < 4; ++e) {
            if (step < L[e]) {
                float gi = acc[0][e], gj = acc[1][e], gf = acc[2][e], go = acc[3][e];
                float nc = c_reg[e] * sigmoidf_(gf) + sigmoidf_(gi) * tanhf_(gj);
                float nh = tanhf_(nc) * sigmoidf_(go);
                c_reg[e] = nc;
                h_reg[e] = f2b(nh);
                nhv[e] = nh;
            }
            __hip_atomic_store(&hout[eoff[e]], h_reg[e],
                               __ATOMIC_RELAXED, __HIP_MEMORY_SCOPE_AGENT);
        }

        // ---- arrive: drain own h-stores to L3, then plain-store the flag ----
        asm volatile("s_waitcnt vmcnt(0)" ::: "memory");
        if (lane == 0)
            __hip_atomic_store(myflag, (unsigned)(step + 1),
                               __ATOMIC_RELAXED, __HIP_MEMORY_SCOPE_AGENT);

        // ---- post-arrive: prefetch + output stores (hidden under poll) ----
        if (mode == 2) gxload(step + 1); else xwindow(step + 1);
#pragma unroll
        for (int e = 0; e < 4; ++e) {
            int bb = rows[e];
            if (step < L[e]) {
                int t_out = dir ? (L[e] - 1 - step) : step;
                out[((size_t)bb * NT + t_out) * (2 * NH) + dir * NH + hidx] = nhv[e];
                if (step == L[e] - 1)
                    h_final[((size_t)dir * NB + bb) * NH + hidx] = nhv[e];
            } else {
                out[((size_t)bb * NT + step) * (2 * NH) + dir * NH + hidx] = 0.f;
            }
        }

        // ---- poll: 96 flags checked in parallel across the wave's lanes ----
        {
            unsigned int tgt = (unsigned)(step + 1);
            while (true) {
                unsigned a = __hip_atomic_load(f1p, __ATOMIC_RELAXED, __HIP_MEMORY_SCOPE_AGENT);
                unsigned b = __hip_atomic_load(f2p, __ATOMIC_RELAXED, __HIP_MEMORY_SCOPE_AGENT);
                if (__all(a >= tgt && b >= tgt)) break;
                __builtin_amdgcn_s_sleep(2);
            }
        }
        __builtin_amdgcn_sched_barrier(0);       // no load hoisting above the poll
        asm volatile("" ::: "memory");
    }
}

// ---------------- final hidden state (f32) -> d_out tail ----------------
__global__ __launch_bounds__(256) void write_state(const float* __restrict__ h_final,
                                                   float* __restrict__ out_state) {
    int i = blockIdx.x * 256 + threadIdx.x;      // over 2*NB*NH
    if (i < 2 * NB * NH) {
        int dir = i / (NB * NH);
        int rem = i - dir * (NB * NH);
        int b = rem / NH, h = rem - (rem / NH) * NH;
        out_state[(size_t)b * (2 * NH) + dir * NH + h] = h_final[i];
    }
}

extern "C" void kernel_launch(void* const* d_in, const int* in_sizes, int n_in,
                              void* d_out, int out_size, void* d_ws, size_t ws_size,
                              hipStream_t stream) {
    const float* seq   = (const float*)d_in[0];
    const int* seq_len = (const int*)d_in[1];
    const float* W_fw  = (const float*)d_in[2];
    const float* b_fw  = (const float*)d_in[3];
    const float* W_bw  = (const float*)d_in[4];
    const float* b_bw  = (const float*)d_in[5];
    float* out = (float*)d_out;

    char* ws = (char*)d_ws;
    size_t off = 0;
    unsigned short* WTf = (unsigned short*)(ws + off); off += (size_t)2 * NG * KTOT * 2; // 15,728,640
    unsigned short* hbufs = (unsigned short*)(ws + off);
    size_t hbuf_bytes = (size_t)3 * 2 * NB * NH * 2;   off += hbuf_bytes;                // 589,824
    float* h_final = (float*)(ws + off);
    size_t hf_bytes = (size_t)2 * NB * NH * 4;         off += hf_bytes;                  // 393,216
    unsigned int* flags = (unsigned int*)(ws + off);
    size_t flag_bytes = (size_t)4 * 96 * 64;           off += flag_bytes;                // 24,576

    _Float16* Gx = (_Float16*)(ws + off);
    size_t gx_bytes = (size_t)2 * 512 * 196608 * 2;      // 402,653,184
    unsigned short* xbf = (unsigned short*)(ws + off);
    size_t xbf_bytes = (size_t)NB * NT * ND * 2;         // 33,554,432

    int mode = (ws_size >= off + gx_bytes) ? 2
             : ((ws_size >= off + xbf_bytes) ? 1 : 0);

    // zero h buffers / h_final / flags (contiguous)
    hipMemsetAsync(hbufs, 0, hbuf_bytes + hf_bytes + flag_bytes, stream);

    transpose_w<<<(KTOT / 64) * (NG / 64), 256, 0, stream>>>(W_fw, WTf);
    transpose_w<<<(KTOT / 64) * (NG / 64), 256, 0, stream>>>(W_bw, WTf + (size_t)NG * KTOT);

    if (mode == 2) {
        gemm_xw<<<1024, 256, 0, stream>>>(seq, WTf, b_fw, b_bw, Gx);
    } else if (mode == 1) {
        int n8 = NB * NT * ND / 8;
        convert_x<<<(n8 + 255) / 256, 256, 0, stream>>>(seq, xbf, n8);
    }

    size_t smem_bytes = 98304;                   // Whf only
    lstm_persistent<<<192, 128, smem_bytes, stream>>>(
        seq, xbf, mode, seq_len, WTf, b_fw, b_bw, Gx,
        hbufs, h_final, out, flags);

    write_state<<<(2 * NB * NH + 255) / 256, 256, 0, stream>>>(
        h_final, out + (size_t)NB * NT * 2 * NH);
}